// Round 16
// baseline (118.443 us; speedup 1.0000x reference)
//
#include <hip/hip_runtime.h>
#include <hip/hip_bf16.h>
#include <hip/hip_fp16.h>
#include <math.h>

#define T 4096
#define NH 8
#define BHN 16
#define NB 64   // buckets per sequence
#define BS 64   // bucket size

using f16x8 = __attribute__((ext_vector_type(8))) _Float16;
using fp16x2_builtin = __attribute__((ext_vector_type(2))) __fp16;
using f32x4 = __attribute__((ext_vector_type(4))) float;

__device__ __forceinline__ f32x4 mfma16f(f16x8 a, f16x8 b, f32x4 c) {
  return __builtin_amdgcn_mfma_f32_16x16x32_f16(a, b, c, 0, 0, 0);
}

// raw v_exp_f32 (1 inst). Valid: exponent args bounded |x|<=~3.2.
__device__ __forceinline__ float fast_exp2(float x) {
  return __builtin_amdgcn_exp2f(x);
}

// fp32x2 -> fp16x2 RTZ pack (1 inst), elem0 in low half
__device__ __forceinline__ unsigned cvtpk_f16(float a, float b) {
  fp16x2_builtin r = __builtin_amdgcn_cvt_pkrtz(a, b);
  unsigned u; __builtin_memcpy(&u, &r, 4); return u;
}
// fp32x2 -> fp16x2 RNE pack (for prep; memory-bound so VALU free)
__device__ __forceinline__ unsigned pk_h2_rn(float a, float b) {
  __half2 h = __float22half2_rn(make_float2(a, b));
  unsigned u; __builtin_memcpy(&u, &h, 4); return u;
}
__device__ __forceinline__ float f4get(const float4& v, int i) {
  return i == 0 ? v.x : i == 1 ? v.y : i == 2 ? v.z : v.w;
}
__device__ __forceinline__ unsigned u4get(const uint4& v, int i) {
  return i == 0 ? v.x : i == 1 ? v.y : i == 2 ? v.z : v.w;
}

// async global->LDS, 16B per lane, linear LDS dest
__device__ __forceinline__ void async_load16(const void* src, void* dst_lds) {
  __builtin_amdgcn_global_load_lds(
      (const __attribute__((address_space(1))) unsigned int*)src,
      (__attribute__((address_space(3))) unsigned int*)dst_lds, 16, 0, 0);
}

// byte-offset swizzles: rows of 128B / 256B, XOR low row bits into 16B-slot bits
#define SWZ128(row, inb) ((((row)) << 7) + ((inb) ^ ((((row)) & 7) << 4)))
#define SWZ256(row, inb) ((((row)) << 8) + ((inb) ^ ((((row)) & 7) << 4)))

// ---------------------------------------------------------------------------
// K1: fused prep + bucket (one qk read). grid (T/64, BH), block 256.
// ---------------------------------------------------------------------------
__global__ __launch_bounds__(256) void k_prepbkt(const float* __restrict__ qk,
                                                 const float* __restrict__ v,
                                                 const float* __restrict__ rot,
                                                 unsigned short* __restrict__ khf,
                                                 unsigned short* __restrict__ vhf,
                                                 float* __restrict__ norm025,
                                                 unsigned char* __restrict__ buckets) {
  __shared__ float sQ[64][65];   // 65-pitch: bucket loop (hot) is 2-way-free
  const int tid = threadIdx.x;
  const int t0 = blockIdx.x * 64;
  const int bh = blockIdx.y;
  const int b = bh >> 3, hh = bh & 7;
  const size_t gbase = (size_t)b * ((size_t)T * 512) + (size_t)hh * 64;

  #pragma unroll
  for (int i = 0; i < 4; ++i) {
    int rr = i * 16 + (tid >> 4);
    int cc = (tid & 15) * 4;
    float4 x = *(const float4*)&qk[gbase + (size_t)(t0 + rr) * 512 + cc];
    sQ[rr][cc] = x.x; sQ[rr][cc + 1] = x.y; sQ[rr][cc + 2] = x.z; sQ[rr][cc + 3] = x.w;
  }
  __syncthreads();

  // ---- prep: 4 threads per token, 16 elems each ----
  {
    const int tok = tid >> 2, q4 = tid & 3;
    float x[16];
    #pragma unroll
    for (int k = 0; k < 16; ++k) x[k] = sQ[tok][q4 * 16 + k];
    float4 y[4];
    const size_t gv = gbase + (size_t)(t0 + tok) * 512 + q4 * 16;
    #pragma unroll
    for (int k = 0; k < 4; ++k) y[k] = *(const float4*)&v[gv + k * 4];

    float ss = 0.f;
    #pragma unroll
    for (int k = 0; k < 16; ++k) ss += x[k] * x[k];
    ss += __shfl_xor(ss, 1);
    ss += __shfl_xor(ss, 2);
    const float invn = rsqrtf(ss);

    const size_t ob = ((size_t)bh * T + (t0 + tok)) * 64 + q4 * 16;
    unsigned kw[8], vw[8];
    #pragma unroll
    for (int p = 0; p < 8; ++p) {
      kw[p] = pk_h2_rn(x[2 * p] * invn, x[2 * p + 1] * invn);
      vw[p] = pk_h2_rn(f4get(y[p >> 1], (p & 1) * 2), f4get(y[p >> 1], (p & 1) * 2 + 1));
    }
    *(uint4*)&khf[ob]     = (uint4){kw[0], kw[1], kw[2], kw[3]};
    *(uint4*)&khf[ob + 8] = (uint4){kw[4], kw[5], kw[6], kw[7]};
    *(uint4*)&vhf[ob]     = (uint4){vw[0], vw[1], vw[2], vw[3]};
    *(uint4*)&vhf[ob + 8] = (uint4){vw[4], vw[5], vw[6], vw[7]};
    if (q4 == 0) norm025[(size_t)bh * T + (t0 + tok)] = 0.125f * ss * invn;
  }

  // ---- bucket: wave wv handles hashes 2wv, 2wv+1; lane = token ----
  const int wv = __builtin_amdgcn_readfirstlane(tid >> 6);
  const int tok = tid & 63;
  const int t = t0 + tok;

  float a0[32], a1[32];
  #pragma unroll
  for (int i = 0; i < 32; ++i) { a0[i] = 0.f; a1[i] = 0.f; }
  for (int f = 0; f < 64; ++f) {
    float qv = sQ[tok][f];
    const float* rp = rot + (size_t)f * (NH * 32) + wv * 64;
    #pragma unroll
    for (int i = 0; i < 32; ++i) {
      a0[i] = fmaf(qv, rp[i], a0[i]);
      a1[i] = fmaf(qv, rp[32 + i], a1[i]);
    }
  }
  #pragma unroll
  for (int h = 0; h < 2; ++h) {
    const float* ac = h ? a1 : a0;
    float maxv = -INFINITY, minv = INFINITY;
    int amax = 0, amin = 0;
    #pragma unroll
    for (int i = 0; i < 32; ++i) {
      if (ac[i] > maxv) { maxv = ac[i]; amax = i; }
      if (ac[i] < minv) { minv = ac[i]; amin = i; }
    }
    int bucket = (maxv >= -minv) ? amax : 32 + amin;
    buckets[((size_t)(2 * wv + h) * BHN + bh) * T + t] = (unsigned char)bucket;
  }
}

// ---------------------------------------------------------------------------
// K2: stable counting argsort per (hash, bh) segment. grid (NH*BH), block 1024.
// Rank via 6-bit radix matching mask (6 ballots).
// ---------------------------------------------------------------------------
__global__ __launch_bounds__(1024) void k_sort(const unsigned char* __restrict__ buckets,
                                               int* __restrict__ perm) {
  __shared__ unsigned short bkt[T];
  __shared__ unsigned short rnk[T];
  __shared__ unsigned int cnt[64 * 64];   // [bucket][chunk]
  __shared__ unsigned int bbase[64];
  __shared__ unsigned int btot[64];

  const int tid = threadIdx.x;
  const int seg = blockIdx.x;
  const unsigned char* bin = buckets + (size_t)seg * T;

  for (int idx = tid; idx < T; idx += 1024) bkt[idx] = bin[idx];
  #pragma unroll
  for (int i = 0; i < 4; ++i) cnt[tid + i * 1024] = 0;
  __syncthreads();

  const int wave = tid >> 6, lane = tid & 63;
  const unsigned long long lt = (1ull << lane) - 1ull;
  #pragma unroll
  for (int cc = 0; cc < 4; ++cc) {
    int chunk = wave * 4 + cc;
    int e = bkt[chunk * 64 + lane];
    unsigned long long m = ~0ull;
    #pragma unroll
    for (int bb = 0; bb < 6; ++bb) {
      unsigned long long mb = __ballot(((e >> bb) & 1) != 0);
      m &= ((e >> bb) & 1) ? mb : ~mb;
    }
    unsigned long long below = m & lt;
    rnk[chunk * 64 + lane] = (unsigned short)__popcll(below);
    if (below == 0ull)
      cnt[e * 64 + chunk] = (unsigned int)__popcll(m);
  }
  __syncthreads();
  if (tid < 64) {
    unsigned int run = 0;
    for (int c = 0; c < 64; ++c) {
      unsigned int v = cnt[tid * 64 + c];
      cnt[tid * 64 + c] = run;
      run += v;
    }
    btot[tid] = run;
  }
  __syncthreads();
  if (tid == 0) {
    unsigned int run = 0;
    for (int bb = 0; bb < 64; ++bb) { bbase[bb] = run; run += btot[bb]; }
  }
  __syncthreads();
  for (int idx = tid; idx < T; idx += 1024) {
    int e = bkt[idx];
    int c = idx >> 6;
    int pos = (int)(bbase[e] + cnt[e * 64 + c] + rnk[idx]);
    perm[(size_t)seg * T + pos] = idx;
  }
}

// ---------------------------------------------------------------------------
// K3: per-bucket attention, TWO buckets per block (n0=2m, n1=2m+1 of same
// (bh,r)), pipelined: bucket1's K staging + V gather issue under bucket0's PV.
// fp16, max-free softmax (raw v_exp), unnormalized o_u (exact combine).
// LDS 32KB -> 5 blocks/CU. grid 4096 (XCD-swizzled), block 256.
// ---------------------------------------------------------------------------
__global__ __launch_bounds__(256, 5) void k_attn16(
    const unsigned short* __restrict__ khf, const unsigned short* __restrict__ vhf,
    const int* __restrict__ perm, const float* __restrict__ norm025,
    __half* __restrict__ o_ws, float* __restrict__ lsum_ws) {
  __shared__ __align__(16) char smem[32768];
  constexpr int LK  = 0;       // K [128 kv][128B] SWZ128; overlay: P [64 q][256B] SWZ256
  constexpr int LVT = 16384;   // V^T [64 d][256B fp16 = 128 tokens] SWZ256

  const int tid = threadIdx.x;
  // XCD-aware bijective swizzle (4096 % 8 == 0): XCD x gets hash r = x.
  const int wg = ((int)blockIdx.x & 7) * 512 + ((int)blockIdx.x >> 3);
  const int m = wg & 31, bh = (wg >> 5) & 15, r = wg >> 9;
  const size_t rowbase = (size_t)bh * T;
  const size_t ps = ((size_t)r * BHN + bh) * T;
  const int n0 = 2 * m, n1 = 2 * m + 1;
  const int b0_own = n0 * 64, b0_prev = ((n0 + 63) & 63) * 64;
  const int b1_own = n1 * 64, b1_prev = n0 * 64;  // n1's prev bucket == n0

  const int wid = tid >> 6, lane = tid & 63;
  const int lr = lane & 15, lg = lane >> 4;
  const int vj0 = (tid & 63) * 2;         // V-token pair
  const int vd0 = (tid >> 6) * 16;        // V d-range

  // ---- prologue: q tokens/scales for both buckets (L2-hot perm reads) ----
  const int qtok0 = perm[ps + b0_own + 16 * wid + lr];
  const float scale0 = norm025[rowbase + qtok0];
  const int qtok1 = perm[ps + b1_own + 16 * wid + lr];
  const float scale1 = norm025[rowbase + qtok1];

  int vt0[2], vt1[2];
  #pragma unroll
  for (int j = 0; j < 2; ++j) {
    int s0 = (vj0 + j < 64) ? (b0_own + vj0 + j) : (b0_prev + vj0 + j - 64);
    int s1 = (vj0 + j < 64) ? (b1_own + vj0 + j) : (b1_prev + vj0 + j - 64);
    vt0[j] = perm[ps + s0];
    vt1[j] = perm[ps + s1];
  }

  // ---- V0 gather (in flight across K0 staging) ----
  uint4 VA0, VA1, VB0, VB1;
  {
    const uint4* pa_ = (const uint4*)&vhf[(rowbase + (size_t)vt0[0]) * 64 + vd0];
    const uint4* pb_ = (const uint4*)&vhf[(rowbase + (size_t)vt0[1]) * 64 + vd0];
    VA0 = pa_[0]; VA1 = pa_[1];
    VB0 = pb_[0]; VB1 = pb_[1];
  }

  // ---- K0 staging: global_load_lds, linear dest + inverse-swizzled source ----
  #pragma unroll
  for (int it = 0; it < 4; ++it) {
    int unit = it * 256 + tid;
    int row = unit >> 3, sl = unit & 7;
    int ssl = sl ^ (row & 7);
    int src = (row < 64) ? (b0_own + row) : (b0_prev + (row - 64));
    int tokr = perm[ps + src];
    async_load16(&khf[(rowbase + (size_t)tokr) * 64 + ssl * 8], smem + LK + unit * 16);
  }
  __syncthreads();  // s2: K0 + V0 in

  f32x4 o[4];
  float ll;

  // ================= bucket 0 =================
  {
    f16x8 bq[2];
    #pragma unroll
    for (int ks = 0; ks < 2; ++ks)
      bq[ks] = *(const f16x8*)(smem + LK + SWZ128(16 * wid + lr, lg * 16 + ks * 64));

    f32x4 c[8];
    #pragma unroll
    for (int t = 0; t < 8; ++t) c[t] = (f32x4){0.f, 0.f, 0.f, 0.f};
    __builtin_amdgcn_s_setprio(1);
    #pragma unroll
    for (int t = 0; t < 8; ++t) {
      #pragma unroll
      for (int ks = 0; ks < 2; ++ks) {
        f16x8 ak = *(const f16x8*)(smem + LK + SWZ128(16 * t + lr, lg * 16 + ks * 64));
        c[t] = mfma16f(ak, bq[ks], c[t]);
      }
    }
    __builtin_amdgcn_s_setprio(0);

    // V^T0 -> LVT (hidden under QK; read after s4)
    #pragma unroll
    for (int dd = 0; dd < 16; ++dd) {
      unsigned aw = (dd < 8) ? u4get(VA0, dd >> 1) : u4get(VA1, (dd - 8) >> 1);
      unsigned bw = (dd < 8) ? u4get(VB0, dd >> 1) : u4get(VB1, (dd - 8) >> 1);
      unsigned w = (dd & 1) ? __builtin_amdgcn_perm(bw, aw, 0x07060302u)
                            : __builtin_amdgcn_perm(bw, aw, 0x05040100u);
      *(unsigned*)(smem + LVT + SWZ256(vd0 + dd, vj0 * 2)) = w;
    }

    // self-mask (position diagonal)
    #pragma unroll
    for (int t = 0; t < 4; ++t)
      #pragma unroll
      for (int rr = 0; rr < 4; ++rr)
        if (16 * t + 4 * lg + rr == 16 * wid + lr) c[t][rr] = -1e30f;

    // max-free softmax
    const float sl2e = scale0 * 1.4426950408889634f;
    ll = 0.f;
    #pragma unroll
    for (int t = 0; t < 8; ++t) {
      #pragma unroll
      for (int rr = 0; rr < 4; ++rr) {
        float e = fast_exp2(c[t][rr] * sl2e);
        c[t][rr] = e;
        ll += e;
      }
    }
    ll += __shfl_xor(ll, 16);
    ll += __shfl_xor(ll, 32);
    if (lg == 0) lsum_ws[ps + qtok0] = ll;

    __syncthreads();  // s3: all K0 reads done

    // P0 over LK
    {
      const int prow = 16 * wid + lr;
      #pragma unroll
      for (int t = 0; t < 8; ++t) {
        unsigned u01 = cvtpk_f16(c[t][0], c[t][1]);
        unsigned u23 = cvtpk_f16(c[t][2], c[t][3]);
        *(uint2*)(smem + LK + SWZ256(prow, 32 * t + 8 * lg)) = make_uint2(u01, u23);
      }
    }
    __syncthreads();  // s4: P0 + V^T0 staged
  }

  // pa0 fragments into regs, then free LK for bucket1's K
  f16x8 pa[4];
  #pragma unroll
  for (int ks = 0; ks < 4; ++ks)
    pa[ks] = *(const f16x8*)(smem + LK + SWZ256(16 * wid + lr, ks * 64 + lg * 16));
  __syncthreads();  // s_pa: all pa0 loaded; LK region free

  // ---- bucket1 staging: K1 -> LK (async), V1 gather (regs); overlaps PV0 ----
  #pragma unroll
  for (int it = 0; it < 4; ++it) {
    int unit = it * 256 + tid;
    int row = unit >> 3, sl = unit & 7;
    int ssl = sl ^ (row & 7);
    int src = (row < 64) ? (b1_own + row) : (b1_prev + (row - 64));
    int tokr = perm[ps + src];
    async_load16(&khf[(rowbase + (size_t)tokr) * 64 + ssl * 8], smem + LK + unit * 16);
  }
  {
    const uint4* pa_ = (const uint4*)&vhf[(rowbase + (size_t)vt1[0]) * 64 + vd0];
    const uint4* pb_ = (const uint4*)&vhf[(rowbase + (size_t)vt1[1]) * 64 + vd0];
    VA0 = pa_[0]; VA1 = pa_[1];
    VB0 = pb_[0]; VB1 = pb_[1];
  }

  // ---- PV0 (reads pa regs + LVT only) ----
  #pragma unroll
  for (int td = 0; td < 4; ++td) o[td] = (f32x4){0.f, 0.f, 0.f, 0.f};
  __builtin_amdgcn_s_setprio(1);
  #pragma unroll
  for (int td = 0; td < 4; ++td) {
    #pragma unroll
    for (int ks = 0; ks < 4; ++ks) {
      f16x8 bv = *(const f16x8*)(smem + LVT + SWZ256(16 * td + lr, lg * 16 + ks * 64));
      o[td] = mfma16f(pa[ks], bv, o[td]);
    }
  }
  __builtin_amdgcn_s_setprio(0);

  // O0 stores (unnormalized, fire-and-forget)
  #pragma unroll
  for (int rr = 0; rr < 4; ++rr) {
    int otok = __shfl(qtok0, 4 * lg + rr);
    size_t gb = (ps + (size_t)otok) * 64 + lr;
    #pragma unroll
    for (int td = 0; td < 4; ++td)
      o_ws[gb + 16 * td] = __float2half(o[td][rr]);
  }

  __syncthreads();  // s2': K1+V1 drained; all PV0 LVT reads done

  // ================= bucket 1 =================
  {
    f16x8 bq[2];
    #pragma unroll
    for (int ks = 0; ks < 2; ++ks)
      bq[ks] = *(const f16x8*)(smem + LK + SWZ128(16 * wid + lr, lg * 16 + ks * 64));

    f32x4 c[8];
    #pragma unroll
    for (int t = 0; t < 8; ++t) c[t] = (f32x4){0.f, 0.f, 0.f, 0.f};
    __builtin_amdgcn_s_setprio(1);
    #pragma unroll
    for (int t = 0; t < 8; ++t) {
      #pragma unroll
      for (int ks = 0; ks < 2; ++ks) {
        f16x8 ak = *(const f16x8*)(smem + LK + SWZ128(16 * t + lr, lg * 16 + ks * 64));
        c[t] = mfma16f(ak, bq[ks], c[t]);
      }
    }
    __builtin_amdgcn_s_setprio(0);

    // V^T1 -> LVT (region free after s2')
    #pragma unroll
    for (int dd = 0; dd < 16; ++dd) {
      unsigned aw = (dd < 8) ? u4get(VA0, dd >> 1) : u4get(VA1, (dd - 8) >> 1);
      unsigned bw = (dd < 8) ? u4get(VB0, dd >> 1) : u4get(VB1, (dd - 8) >> 1);
      unsigned w = (dd & 1) ? __builtin_amdgcn_perm(bw, aw, 0x07060302u)
                            : __builtin_amdgcn_perm(bw, aw, 0x05040100u);
      *(unsigned*)(smem + LVT + SWZ256(vd0 + dd, vj0 * 2)) = w;
    }

    #pragma unroll
    for (int t = 0; t < 4; ++t)
      #pragma unroll
      for (int rr = 0; rr < 4; ++rr)
        if (16 * t + 4 * lg + rr == 16 * wid + lr) c[t][rr] = -1e30f;

    const float sl2e = scale1 * 1.4426950408889634f;
    ll = 0.f;
    #pragma unroll
    for (int t = 0; t < 8; ++t) {
      #pragma unroll
      for (int rr = 0; rr < 4; ++rr) {
        float e = fast_exp2(c[t][rr] * sl2e);
        c[t][rr] = e;
        ll += e;
      }
    }
    ll += __shfl_xor(ll, 16);
    ll += __shfl_xor(ll, 32);
    if (lg == 0) lsum_ws[ps + qtok1] = ll;

    __syncthreads();  // s3': all K1 reads done

    {
      const int prow = 16 * wid + lr;
      #pragma unroll
      for (int t = 0; t < 8; ++t) {
        unsigned u01 = cvtpk_f16(c[t][0], c[t][1]);
        unsigned u23 = cvtpk_f16(c[t][2], c[t][3]);
        *(uint2*)(smem + LK + SWZ256(prow, 32 * t + 8 * lg)) = make_uint2(u01, u23);
      }
    }
    __syncthreads();  // s4': P1 + V^T1 staged
  }

  #pragma unroll
  for (int ks = 0; ks < 4; ++ks)
    pa[ks] = *(const f16x8*)(smem + LK + SWZ256(16 * wid + lr, ks * 64 + lg * 16));
  #pragma unroll
  for (int td = 0; td < 4; ++td) o[td] = (f32x4){0.f, 0.f, 0.f, 0.f};
  __builtin_amdgcn_s_setprio(1);
  #pragma unroll
  for (int td = 0; td < 4; ++td) {
    #pragma unroll
    for (int ks = 0; ks < 4; ++ks) {
      f16x8 bv = *(const f16x8*)(smem + LVT + SWZ256(16 * td + lr, lg * 16 + ks * 64));
      o[td] = mfma16f(pa[ks], bv, o[td]);
    }
  }
  __builtin_amdgcn_s_setprio(0);

  #pragma unroll
  for (int rr = 0; rr < 4; ++rr) {
    int otok = __shfl(qtok1, 4 * lg + rr);
    size_t gb = (ps + (size_t)otok) * 64 + lr;
    #pragma unroll
    for (int td = 0; td < 4; ++td)
      o_ws[gb + 16 * td] = __float2half(o[td][rr]);
  }
}

// ---------------------------------------------------------------------------
// K4: exact combine: out = (sum_r o_u[r]) / (sum_r l[r]). uint4 (16B) o_ws
// loads, 8 d per thread. grid (BH*T*8/256), block 256.
// ---------------------------------------------------------------------------
__global__ __launch_bounds__(256) void k_combine(const __half* __restrict__ o_ws,
                                                 const float* __restrict__ lsum_ws,
                                                 float* __restrict__ out) {
  const int gid = blockIdx.x * 256 + threadIdx.x;
  const int d8 = (gid & 7) * 8;
  const int row = gid >> 3;   // bh*T + t
  const int bh = row >> 12;
  const int t = row & (T - 1);

  float lsum = 0.f;
  #pragma unroll
  for (int r = 0; r < 8; ++r)
    lsum += lsum_ws[((size_t)r * BHN + bh) * T + t];
  float rcp = 1.0f / lsum;

  float acc[8];
  #pragma unroll
  for (int k = 0; k < 8; ++k) acc[k] = 0.f;
  #pragma unroll
  for (int r = 0; r < 8; ++r) {
    uint4 u = *(const uint4*)&o_ws[(((size_t)r * BHN + bh) * T + t) * 64 + d8];
    #pragma unroll
    for (int k = 0; k < 4; ++k) {
      __half2 h; __builtin_memcpy(&h, k == 0 ? &u.x : k == 1 ? &u.y : k == 2 ? &u.z : &u.w, 4);
      float2 f = __half22float2(h);
      acc[2 * k] += f.x; acc[2 * k + 1] += f.y;
    }
  }
  const int b = bh >> 3, hh = bh & 7;
  float* op = &out[(((size_t)b * T + t) * 8 + hh) * 64 + d8];
  *(float4*)&op[0] = make_float4(acc[0] * rcp, acc[1] * rcp, acc[2] * rcp, acc[3] * rcp);
  *(float4*)&op[4] = make_float4(acc[4] * rcp, acc[5] * rcp, acc[6] * rcp, acc[7] * rcp);
}

// ---------------------------------------------------------------------------
extern "C" void kernel_launch(void* const* d_in, const int* in_sizes, int n_in,
                              void* d_out, int out_size, void* d_ws, size_t ws_size,
                              hipStream_t stream) {
  const float* qk  = (const float*)d_in[0];
  const float* v   = (const float*)d_in[1];
  const float* rot = (const float*)d_in[2];
  float* out = (float*)d_out;

  // workspace layout (bytes) — total 95,158,272 (within proven budget)
  char* ws = (char*)d_ws;
  __half* o_ws          = (__half*)(ws);                      // 67,108,864
  int* perm             = (int*)(ws + 67108864);              //  8,388,608
  unsigned char* bkts   = (unsigned char*)(ws + 75497472);    //    524,288
  float* lsum_ws        = (float*)(ws + 76021760);            //  2,097,152
  float* norm025        = (float*)(ws + 78118912);            //    262,144
  unsigned short* khf   = (unsigned short*)(ws + 78381056);   //  8,388,608
  unsigned short* vhf   = (unsigned short*)(ws + 86769664);   //  8,388,608

  k_prepbkt<<<dim3(T / 64, BHN), 256, 0, stream>>>(qk, v, rot, khf, vhf, norm025, bkts);
  k_sort<<<dim3(NH * BHN), 1024, 0, stream>>>(bkts, perm);
  k_attn16<<<dim3((NB / 2) * BHN * NH), 256, 0, stream>>>(khf, vhf, perm, norm025,
                                                          o_ws, lsum_ws);
  k_combine<<<dim3((BHN * T * 8) / 256), 256, 0, stream>>>(o_ws, lsum_ws, out);
}

// Round 17
// 110.290 us; speedup vs baseline: 1.0739x; 1.0739x over previous
//
#include <hip/hip_runtime.h>
#include <hip/hip_bf16.h>
#include <hip/hip_fp16.h>
#include <math.h>

#define T 4096
#define NH 8
#define BHN 16
#define NB 64   // buckets per sequence
#define BS 64   // bucket size

using f16x8 = __attribute__((ext_vector_type(8))) _Float16;
using fp16x2_builtin = __attribute__((ext_vector_type(2))) __fp16;
using f32x4 = __attribute__((ext_vector_type(4))) float;

__device__ __forceinline__ f32x4 mfma16f(f16x8 a, f16x8 b, f32x4 c) {
  return __builtin_amdgcn_mfma_f32_16x16x32_f16(a, b, c, 0, 0, 0);
}

// raw v_exp_f32 (1 inst). Valid: exponent args bounded |x|<=~3.2.
__device__ __forceinline__ float fast_exp2(float x) {
  return __builtin_amdgcn_exp2f(x);
}

// fp32x2 -> fp16x2 RTZ pack (1 inst), elem0 in low half
__device__ __forceinline__ unsigned cvtpk_f16(float a, float b) {
  fp16x2_builtin r = __builtin_amdgcn_cvt_pkrtz(a, b);
  unsigned u; __builtin_memcpy(&u, &r, 4); return u;
}
// fp32x2 -> fp16x2 RNE pack (for prep; memory-bound so VALU free)
__device__ __forceinline__ unsigned pk_h2_rn(float a, float b) {
  __half2 h = __float22half2_rn(make_float2(a, b));
  unsigned u; __builtin_memcpy(&u, &h, 4); return u;
}
__device__ __forceinline__ float f4get(const float4& v, int i) {
  return i == 0 ? v.x : i == 1 ? v.y : i == 2 ? v.z : v.w;
}
__device__ __forceinline__ unsigned u4get(const uint4& v, int i) {
  return i == 0 ? v.x : i == 1 ? v.y : i == 2 ? v.z : v.w;
}

// async global->LDS, 16B per lane, linear LDS dest
__device__ __forceinline__ void async_load16(const void* src, void* dst_lds) {
  __builtin_amdgcn_global_load_lds(
      (const __attribute__((address_space(1))) unsigned int*)src,
      (__attribute__((address_space(3))) unsigned int*)dst_lds, 16, 0, 0);
}

// byte-offset swizzles: rows of 128B / 256B, XOR low row bits into 16B-slot bits
#define SWZ128(row, inb) ((((row)) << 7) + ((inb) ^ ((((row)) & 7) << 4)))
#define SWZ256(row, inb) ((((row)) << 8) + ((inb) ^ ((((row)) & 7) << 4)))

// ---------------------------------------------------------------------------
// K1: fused prep + bucket (one qk read). grid (T/64, BH), block 256.
// ---------------------------------------------------------------------------
__global__ __launch_bounds__(256) void k_prepbkt(const float* __restrict__ qk,
                                                 const float* __restrict__ v,
                                                 const float* __restrict__ rot,
                                                 unsigned short* __restrict__ khf,
                                                 unsigned short* __restrict__ vhf,
                                                 float* __restrict__ norm025,
                                                 unsigned char* __restrict__ buckets) {
  __shared__ float sQ[64][65];   // 65-pitch: bucket loop (hot) is 2-way-free
  const int tid = threadIdx.x;
  const int t0 = blockIdx.x * 64;
  const int bh = blockIdx.y;
  const int b = bh >> 3, hh = bh & 7;
  const size_t gbase = (size_t)b * ((size_t)T * 512) + (size_t)hh * 64;

  #pragma unroll
  for (int i = 0; i < 4; ++i) {
    int rr = i * 16 + (tid >> 4);
    int cc = (tid & 15) * 4;
    float4 x = *(const float4*)&qk[gbase + (size_t)(t0 + rr) * 512 + cc];
    sQ[rr][cc] = x.x; sQ[rr][cc + 1] = x.y; sQ[rr][cc + 2] = x.z; sQ[rr][cc + 3] = x.w;
  }
  __syncthreads();

  // ---- prep: 4 threads per token, 16 elems each ----
  {
    const int tok = tid >> 2, q4 = tid & 3;
    float x[16];
    #pragma unroll
    for (int k = 0; k < 16; ++k) x[k] = sQ[tok][q4 * 16 + k];
    float4 y[4];
    const size_t gv = gbase + (size_t)(t0 + tok) * 512 + q4 * 16;
    #pragma unroll
    for (int k = 0; k < 4; ++k) y[k] = *(const float4*)&v[gv + k * 4];

    float ss = 0.f;
    #pragma unroll
    for (int k = 0; k < 16; ++k) ss += x[k] * x[k];
    ss += __shfl_xor(ss, 1);
    ss += __shfl_xor(ss, 2);
    const float invn = rsqrtf(ss);

    const size_t ob = ((size_t)bh * T + (t0 + tok)) * 64 + q4 * 16;
    unsigned kw[8], vw[8];
    #pragma unroll
    for (int p = 0; p < 8; ++p) {
      kw[p] = pk_h2_rn(x[2 * p] * invn, x[2 * p + 1] * invn);
      vw[p] = pk_h2_rn(f4get(y[p >> 1], (p & 1) * 2), f4get(y[p >> 1], (p & 1) * 2 + 1));
    }
    *(uint4*)&khf[ob]     = (uint4){kw[0], kw[1], kw[2], kw[3]};
    *(uint4*)&khf[ob + 8] = (uint4){kw[4], kw[5], kw[6], kw[7]};
    *(uint4*)&vhf[ob]     = (uint4){vw[0], vw[1], vw[2], vw[3]};
    *(uint4*)&vhf[ob + 8] = (uint4){vw[4], vw[5], vw[6], vw[7]};
    if (q4 == 0) norm025[(size_t)bh * T + (t0 + tok)] = 0.125f * ss * invn;
  }

  // ---- bucket: wave wv handles hashes 2wv, 2wv+1; lane = token ----
  const int wv = __builtin_amdgcn_readfirstlane(tid >> 6);
  const int tok = tid & 63;
  const int t = t0 + tok;

  float a0[32], a1[32];
  #pragma unroll
  for (int i = 0; i < 32; ++i) { a0[i] = 0.f; a1[i] = 0.f; }
  for (int f = 0; f < 64; ++f) {
    float qv = sQ[tok][f];
    const float* rp = rot + (size_t)f * (NH * 32) + wv * 64;
    #pragma unroll
    for (int i = 0; i < 32; ++i) {
      a0[i] = fmaf(qv, rp[i], a0[i]);
      a1[i] = fmaf(qv, rp[32 + i], a1[i]);
    }
  }
  #pragma unroll
  for (int h = 0; h < 2; ++h) {
    const float* ac = h ? a1 : a0;
    float maxv = -INFINITY, minv = INFINITY;
    int amax = 0, amin = 0;
    #pragma unroll
    for (int i = 0; i < 32; ++i) {
      if (ac[i] > maxv) { maxv = ac[i]; amax = i; }
      if (ac[i] < minv) { minv = ac[i]; amin = i; }
    }
    int bucket = (maxv >= -minv) ? amax : 32 + amin;
    buckets[((size_t)(2 * wv + h) * BHN + bh) * T + t] = (unsigned char)bucket;
  }
}

// ---------------------------------------------------------------------------
// K2: stable counting argsort per (hash, bh) segment. grid (NH*BH), block 1024.
// Rank via 6-bit radix matching mask (6 ballots).
// ---------------------------------------------------------------------------
__global__ __launch_bounds__(1024) void k_sort(const unsigned char* __restrict__ buckets,
                                               int* __restrict__ perm) {
  __shared__ unsigned short bkt[T];
  __shared__ unsigned short rnk[T];
  __shared__ unsigned int cnt[64 * 64];   // [bucket][chunk]
  __shared__ unsigned int bbase[64];
  __shared__ unsigned int btot[64];

  const int tid = threadIdx.x;
  const int seg = blockIdx.x;
  const unsigned char* bin = buckets + (size_t)seg * T;

  for (int idx = tid; idx < T; idx += 1024) bkt[idx] = bin[idx];
  #pragma unroll
  for (int i = 0; i < 4; ++i) cnt[tid + i * 1024] = 0;
  __syncthreads();

  const int wave = tid >> 6, lane = tid & 63;
  const unsigned long long lt = (1ull << lane) - 1ull;
  #pragma unroll
  for (int cc = 0; cc < 4; ++cc) {
    int chunk = wave * 4 + cc;
    int e = bkt[chunk * 64 + lane];
    unsigned long long m = ~0ull;
    #pragma unroll
    for (int bb = 0; bb < 6; ++bb) {
      unsigned long long mb = __ballot(((e >> bb) & 1) != 0);
      m &= ((e >> bb) & 1) ? mb : ~mb;
    }
    unsigned long long below = m & lt;
    rnk[chunk * 64 + lane] = (unsigned short)__popcll(below);
    if (below == 0ull)
      cnt[e * 64 + chunk] = (unsigned int)__popcll(m);
  }
  __syncthreads();
  if (tid < 64) {
    unsigned int run = 0;
    for (int c = 0; c < 64; ++c) {
      unsigned int v = cnt[tid * 64 + c];
      cnt[tid * 64 + c] = run;
      run += v;
    }
    btot[tid] = run;
  }
  __syncthreads();
  if (tid == 0) {
    unsigned int run = 0;
    for (int bb = 0; bb < 64; ++bb) { bbase[bb] = run; run += btot[bb]; }
  }
  __syncthreads();
  for (int idx = tid; idx < T; idx += 1024) {
    int e = bkt[idx];
    int c = idx >> 6;
    int pos = (int)(bbase[e] + cnt[e * 64 + c] + rnk[idx]);
    perm[(size_t)seg * T + pos] = idx;
  }
}

// ---------------------------------------------------------------------------
// K3: per-bucket attention (round-15 proven structure), fp16, max-free
// softmax (raw v_exp), unnormalized o_u (exact combine). One bucket/block.
// LDS 32KB -> 5 blocks/CU. grid 8192 (XCD-swizzled), block 256.
// ---------------------------------------------------------------------------
__global__ __launch_bounds__(256, 5) void k_attn17(
    const unsigned short* __restrict__ khf, const unsigned short* __restrict__ vhf,
    const int* __restrict__ perm, const float* __restrict__ norm025,
    __half* __restrict__ o_ws, float* __restrict__ lsum_ws) {
  __shared__ __align__(16) char smem[32768];
  constexpr int LK  = 0;       // ph1: Khat [128 kv][128B fp16] SWZ128
  constexpr int LP  = 0;       // ph2: P [64 q][256B fp16 = 128 kv] SWZ256
  constexpr int LVT = 16384;   // V^T [64 d][256B fp16 = 128 tokens] SWZ256

  const int tid = threadIdx.x;
  // XCD-aware bijective swizzle (8192 % 8 == 0): XCD x gets hash r = x.
  const int wg = ((int)blockIdx.x & 7) * 1024 + ((int)blockIdx.x >> 3);
  const int n = wg & 63, bh = (wg >> 6) & 15, r = wg >> 10;
  const size_t rowbase = (size_t)bh * T;
  const size_t ps = ((size_t)r * BHN + bh) * T;
  const int base_own = n * 64;
  const int base_prev = ((n + 63) & 63) * 64;

  const int wid = tid >> 6, lane = tid & 63;
  const int lr = lane & 15, lg = lane >> 4;

  const int qtok = perm[ps + base_own + 16 * wid + lr];
  const float scale = norm025[rowbase + qtok];

  // ---- V gather: 2 tokens x 16 d per thread (issue early, in flight) ----
  const int vj0 = (tid & 63) * 2;         // token pair (vj0, vj0+1)
  const int vd0 = (tid >> 6) * 16;        // d range [vd0, vd0+16)
  int vt[2];
  #pragma unroll
  for (int j = 0; j < 2; ++j) {
    int src = (vj0 + j < 64) ? (base_own + vj0 + j) : (base_prev + vj0 + j - 64);
    vt[j] = perm[ps + src];
  }
  uint4 VA0, VA1, VB0, VB1;
  {
    const uint4* pa = (const uint4*)&vhf[(rowbase + (size_t)vt[0]) * 64 + vd0];
    const uint4* pb = (const uint4*)&vhf[(rowbase + (size_t)vt[1]) * 64 + vd0];
    VA0 = pa[0]; VA1 = pa[1];
    VB0 = pb[0]; VB1 = pb[1];
  }

  // ---- K staging: global_load_lds, linear dest + inverse-swizzled source ----
  #pragma unroll
  for (int it = 0; it < 4; ++it) {
    int unit = it * 256 + tid;
    int row = unit >> 3, sl = unit & 7;
    int ssl = sl ^ (row & 7);
    int src = (row < 64) ? (base_own + row) : (base_prev + (row - 64));
    int tokr = perm[ps + src];
    async_load16(&khf[(rowbase + (size_t)tokr) * 64 + ssl * 8], smem + LK + unit * 16);
  }
  __syncthreads();  // s2: K staged

  // B frag = own q row, held in regs before P overlays LK
  f16x8 bq[2];
  #pragma unroll
  for (int ks = 0; ks < 2; ++ks)
    bq[ks] = *(const f16x8*)(smem + LK + SWZ128(16 * wid + lr, lg * 16 + ks * 64));

  // ---- QK: S^T[kv][q] = K . Q^T, 16 MFMA ----
  f32x4 c[8];
  #pragma unroll
  for (int t = 0; t < 8; ++t) c[t] = (f32x4){0.f, 0.f, 0.f, 0.f};
  #pragma unroll
  for (int t = 0; t < 8; ++t) {
    #pragma unroll
    for (int ks = 0; ks < 2; ++ks) {
      f16x8 ak = *(const f16x8*)(smem + LK + SWZ128(16 * t + lr, lg * 16 + ks * 64));
      c[t] = mfma16f(ak, bq[ks], c[t]);
    }
  }

  // ---- V^T -> LVT (fresh region, hidden under QK; read only after s4) ----
  #pragma unroll
  for (int dd = 0; dd < 16; ++dd) {
    unsigned aw = (dd < 8) ? u4get(VA0, dd >> 1) : u4get(VA1, (dd - 8) >> 1);
    unsigned bw = (dd < 8) ? u4get(VB0, dd >> 1) : u4get(VB1, (dd - 8) >> 1);
    unsigned w = (dd & 1) ? __builtin_amdgcn_perm(bw, aw, 0x07060302u)
                          : __builtin_amdgcn_perm(bw, aw, 0x05040100u);
    *(unsigned*)(smem + LVT + SWZ256(vd0 + dd, vj0 * 2)) = w;
  }

  // ---- self-mask: position diagonal (q row == kv row in 0..63) ----
  #pragma unroll
  for (int t = 0; t < 4; ++t) {
    #pragma unroll
    for (int rr = 0; rr < 4; ++rr)
      if (16 * t + 4 * lg + rr == 16 * wid + lr) c[t][rr] = -1e30f;
  }

  // ---- MAX-FREE softmax: |score| <= scale (<= ~2.2), raw v_exp_f32 ----
  const float sl2e = scale * 1.4426950408889634f;
  float ll = 0.f;
  #pragma unroll
  for (int t = 0; t < 8; ++t) {
    #pragma unroll
    for (int rr = 0; rr < 4; ++rr) {
      float e = fast_exp2(c[t][rr] * sl2e);
      c[t][rr] = e;
      ll += e;
    }
  }
  ll += __shfl_xor(ll, 16);
  ll += __shfl_xor(ll, 32);
  if (lg == 0) lsum_ws[ps + qtok] = ll;   // raw sum (no log)

  __syncthreads();  // s3: all LK reads done

  // ---- P (unnormalized fp16, RTZ pack) over LK as [64 q][256B] ----
  {
    const int prow = 16 * wid + lr;
    #pragma unroll
    for (int t = 0; t < 8; ++t) {
      unsigned u01 = cvtpk_f16(c[t][0], c[t][1]);
      unsigned u23 = cvtpk_f16(c[t][2], c[t][3]);
      *(uint2*)(smem + LP + SWZ256(prow, 32 * t + 8 * lg)) = make_uint2(u01, u23);
    }
  }
  __syncthreads();  // s4: P + V^T staged

  // ---- PV: A = P row (q = 16w+lr), B = V^T rows (d), 16 MFMA ----
  f16x8 pa[4];
  #pragma unroll
  for (int ks = 0; ks < 4; ++ks)
    pa[ks] = *(const f16x8*)(smem + LP + SWZ256(16 * wid + lr, ks * 64 + lg * 16));
  f32x4 o[4];
  #pragma unroll
  for (int td = 0; td < 4; ++td) o[td] = (f32x4){0.f, 0.f, 0.f, 0.f};
  #pragma unroll
  for (int td = 0; td < 4; ++td) {
    #pragma unroll
    for (int ks = 0; ks < 4; ++ks) {
      f16x8 bv = *(const f16x8*)(smem + LVT + SWZ256(16 * td + lr, lg * 16 + ks * 64));
      o[td] = mfma16f(pa[ks], bv, o[td]);
    }
  }

  // ---- UNNORMALIZED fp16 O stores (otok via shuffle from qtok) ----
  #pragma unroll
  for (int rr = 0; rr < 4; ++rr) {
    int otok = __shfl(qtok, 4 * lg + rr);
    size_t gb = (ps + (size_t)otok) * 64 + lr;
    #pragma unroll
    for (int td = 0; td < 4; ++td)
      o_ws[gb + 16 * td] = __float2half(o[td][rr]);
  }
}

// ---------------------------------------------------------------------------
// K4: exact combine: out = (sum_r o_u[r]) / (sum_r l[r]). uint4 (16B) o_ws
// loads, 8 d per thread. grid (BH*T*8/256), block 256.
// ---------------------------------------------------------------------------
__global__ __launch_bounds__(256) void k_combine(const __half* __restrict__ o_ws,
                                                 const float* __restrict__ lsum_ws,
                                                 float* __restrict__ out) {
  const int gid = blockIdx.x * 256 + threadIdx.x;
  const int d8 = (gid & 7) * 8;
  const int row = gid >> 3;   // bh*T + t
  const int bh = row >> 12;
  const int t = row & (T - 1);

  float lsum = 0.f;
  #pragma unroll
  for (int r = 0; r < 8; ++r)
    lsum += lsum_ws[((size_t)r * BHN + bh) * T + t];
  float rcp = 1.0f / lsum;

  float acc[8];
  #pragma unroll
  for (int k = 0; k < 8; ++k) acc[k] = 0.f;
  #pragma unroll
  for (int r = 0; r < 8; ++r) {
    uint4 u = *(const uint4*)&o_ws[(((size_t)r * BHN + bh) * T + t) * 64 + d8];
    #pragma unroll
    for (int k = 0; k < 4; ++k) {
      __half2 h; __builtin_memcpy(&h, k == 0 ? &u.x : k == 1 ? &u.y : k == 2 ? &u.z : &u.w, 4);
      float2 f = __half22float2(h);
      acc[2 * k] += f.x; acc[2 * k + 1] += f.y;
    }
  }
  const int b = bh >> 3, hh = bh & 7;
  float* op = &out[(((size_t)b * T + t) * 8 + hh) * 64 + d8];
  *(float4*)&op[0] = make_float4(acc[0] * rcp, acc[1] * rcp, acc[2] * rcp, acc[3] * rcp);
  *(float4*)&op[4] = make_float4(acc[4] * rcp, acc[5] * rcp, acc[6] * rcp, acc[7] * rcp);
}

// ---------------------------------------------------------------------------
extern "C" void kernel_launch(void* const* d_in, const int* in_sizes, int n_in,
                              void* d_out, int out_size, void* d_ws, size_t ws_size,
                              hipStream_t stream) {
  const float* qk  = (const float*)d_in[0];
  const float* v   = (const float*)d_in[1];
  const float* rot = (const float*)d_in[2];
  float* out = (float*)d_out;

  // workspace layout (bytes) — total 95,158,272 (within proven budget)
  char* ws = (char*)d_ws;
  __half* o_ws          = (__half*)(ws);                      // 67,108,864
  int* perm             = (int*)(ws + 67108864);              //  8,388,608
  unsigned char* bkts   = (unsigned char*)(ws + 75497472);    //    524,288
  float* lsum_ws        = (float*)(ws + 76021760);            //  2,097,152
  float* norm025        = (float*)(ws + 78118912);            //    262,144
  unsigned short* khf   = (unsigned short*)(ws + 78381056);   //  8,388,608
  unsigned short* vhf   = (unsigned short*)(ws + 86769664);   //  8,388,608

  k_prepbkt<<<dim3(T / 64, BHN), 256, 0, stream>>>(qk, v, rot, khf, vhf, norm025, bkts);
  k_sort<<<dim3(NH * BHN), 1024, 0, stream>>>(bkts, perm);
  k_attn17<<<dim3(NB * BHN * NH), 256, 0, stream>>>(khf, vhf, perm, norm025,
                                                    o_ws, lsum_ws);
  k_combine<<<dim3((BHN * T * 8) / 256), 256, 0, stream>>>(o_ws, lsum_ws, out);
}

// Round 18
// 108.899 us; speedup vs baseline: 1.0876x; 1.0128x over previous
//
#include <hip/hip_runtime.h>
#include <hip/hip_bf16.h>
#include <hip/hip_fp16.h>
#include <math.h>

#define T 4096
#define NH 8
#define BHN 16
#define NB 64   // buckets per sequence
#define BS 64   // bucket size

using f16x8 = __attribute__((ext_vector_type(8))) _Float16;
using fp16x2_builtin = __attribute__((ext_vector_type(2))) __fp16;
using f32x4 = __attribute__((ext_vector_type(4))) float;

__device__ __forceinline__ f32x4 mfma16f(f16x8 a, f16x8 b, f32x4 c) {
  return __builtin_amdgcn_mfma_f32_16x16x32_f16(a, b, c, 0, 0, 0);
}

// raw v_exp_f32 (1 inst). Valid: exponent args bounded |x|<=~3.2.
__device__ __forceinline__ float fast_exp2(float x) {
  return __builtin_amdgcn_exp2f(x);
}

// fp32x2 -> fp16x2 RTZ pack (1 inst), elem0 in low half
__device__ __forceinline__ unsigned cvtpk_f16(float a, float b) {
  fp16x2_builtin r = __builtin_amdgcn_cvt_pkrtz(a, b);
  unsigned u; __builtin_memcpy(&u, &r, 4); return u;
}
// fp32x2 -> fp16x2 RNE pack (for prep; memory-bound so VALU free)
__device__ __forceinline__ unsigned pk_h2_rn(float a, float b) {
  __half2 h = __float22half2_rn(make_float2(a, b));
  unsigned u; __builtin_memcpy(&u, &h, 4); return u;
}
__device__ __forceinline__ float f4get(const float4& v, int i) {
  return i == 0 ? v.x : i == 1 ? v.y : i == 2 ? v.z : v.w;
}
__device__ __forceinline__ unsigned u4get(const uint4& v, int i) {
  return i == 0 ? v.x : i == 1 ? v.y : i == 2 ? v.z : v.w;
}

// async global->LDS, 16B per lane, linear LDS dest
__device__ __forceinline__ void async_load16(const void* src, void* dst_lds) {
  __builtin_amdgcn_global_load_lds(
      (const __attribute__((address_space(1))) unsigned int*)src,
      (__attribute__((address_space(3))) unsigned int*)dst_lds, 16, 0, 0);
}

// byte-offset swizzles: rows of 128B / 256B, XOR low row bits into 16B-slot bits
#define SWZ128(row, inb) ((((row)) << 7) + ((inb) ^ ((((row)) & 7) << 4)))
#define SWZ256(row, inb) ((((row)) << 8) + ((inb) ^ ((((row)) & 7) << 4)))

// ---------------------------------------------------------------------------
// K1: fused prep + bucket (one qk read). grid (T/64, BH), block 256.
// ---------------------------------------------------------------------------
__global__ __launch_bounds__(256) void k_prepbkt(const float* __restrict__ qk,
                                                 const float* __restrict__ v,
                                                 const float* __restrict__ rot,
                                                 unsigned short* __restrict__ khf,
                                                 unsigned short* __restrict__ vhf,
                                                 float* __restrict__ norm025,
                                                 unsigned char* __restrict__ buckets) {
  __shared__ float sQ[64][65];   // 65-pitch: bucket loop (hot) is 2-way-free
  const int tid = threadIdx.x;
  const int t0 = blockIdx.x * 64;
  const int bh = blockIdx.y;
  const int b = bh >> 3, hh = bh & 7;
  const size_t gbase = (size_t)b * ((size_t)T * 512) + (size_t)hh * 64;

  #pragma unroll
  for (int i = 0; i < 4; ++i) {
    int rr = i * 16 + (tid >> 4);
    int cc = (tid & 15) * 4;
    float4 x = *(const float4*)&qk[gbase + (size_t)(t0 + rr) * 512 + cc];
    sQ[rr][cc] = x.x; sQ[rr][cc + 1] = x.y; sQ[rr][cc + 2] = x.z; sQ[rr][cc + 3] = x.w;
  }
  __syncthreads();

  // ---- prep: 4 threads per token, 16 elems each ----
  {
    const int tok = tid >> 2, q4 = tid & 3;
    float x[16];
    #pragma unroll
    for (int k = 0; k < 16; ++k) x[k] = sQ[tok][q4 * 16 + k];
    float4 y[4];
    const size_t gv = gbase + (size_t)(t0 + tok) * 512 + q4 * 16;
    #pragma unroll
    for (int k = 0; k < 4; ++k) y[k] = *(const float4*)&v[gv + k * 4];

    float ss = 0.f;
    #pragma unroll
    for (int k = 0; k < 16; ++k) ss += x[k] * x[k];
    ss += __shfl_xor(ss, 1);
    ss += __shfl_xor(ss, 2);
    const float invn = rsqrtf(ss);

    const size_t ob = ((size_t)bh * T + (t0 + tok)) * 64 + q4 * 16;
    unsigned kw[8], vw[8];
    #pragma unroll
    for (int p = 0; p < 8; ++p) {
      kw[p] = pk_h2_rn(x[2 * p] * invn, x[2 * p + 1] * invn);
      vw[p] = pk_h2_rn(f4get(y[p >> 1], (p & 1) * 2), f4get(y[p >> 1], (p & 1) * 2 + 1));
    }
    *(uint4*)&khf[ob]     = (uint4){kw[0], kw[1], kw[2], kw[3]};
    *(uint4*)&khf[ob + 8] = (uint4){kw[4], kw[5], kw[6], kw[7]};
    *(uint4*)&vhf[ob]     = (uint4){vw[0], vw[1], vw[2], vw[3]};
    *(uint4*)&vhf[ob + 8] = (uint4){vw[4], vw[5], vw[6], vw[7]};
    if (q4 == 0) norm025[(size_t)bh * T + (t0 + tok)] = 0.125f * ss * invn;
  }

  // ---- bucket: wave wv handles hashes 2wv, 2wv+1; lane = token ----
  const int wv = __builtin_amdgcn_readfirstlane(tid >> 6);
  const int tok = tid & 63;
  const int t = t0 + tok;

  float a0[32], a1[32];
  #pragma unroll
  for (int i = 0; i < 32; ++i) { a0[i] = 0.f; a1[i] = 0.f; }
  for (int f = 0; f < 64; ++f) {
    float qv = sQ[tok][f];
    const float* rp = rot + (size_t)f * (NH * 32) + wv * 64;
    #pragma unroll
    for (int i = 0; i < 32; ++i) {
      a0[i] = fmaf(qv, rp[i], a0[i]);
      a1[i] = fmaf(qv, rp[32 + i], a1[i]);
    }
  }
  #pragma unroll
  for (int h = 0; h < 2; ++h) {
    const float* ac = h ? a1 : a0;
    float maxv = -INFINITY, minv = INFINITY;
    int amax = 0, amin = 0;
    #pragma unroll
    for (int i = 0; i < 32; ++i) {
      if (ac[i] > maxv) { maxv = ac[i]; amax = i; }
      if (ac[i] < minv) { minv = ac[i]; amin = i; }
    }
    int bucket = (maxv >= -minv) ? amax : 32 + amin;
    buckets[((size_t)(2 * wv + h) * BHN + bh) * T + t] = (unsigned char)bucket;
  }
}

// ---------------------------------------------------------------------------
// K2: stable counting argsort per (hash, bh) segment. grid (NH*BH), block 1024.
// Rank via 6-bit radix matching mask (6 ballots).
// ---------------------------------------------------------------------------
__global__ __launch_bounds__(1024) void k_sort(const unsigned char* __restrict__ buckets,
                                               int* __restrict__ perm) {
  __shared__ unsigned short bkt[T];
  __shared__ unsigned short rnk[T];
  __shared__ unsigned int cnt[64 * 64];   // [bucket][chunk]
  __shared__ unsigned int bbase[64];
  __shared__ unsigned int btot[64];

  const int tid = threadIdx.x;
  const int seg = blockIdx.x;
  const unsigned char* bin = buckets + (size_t)seg * T;

  for (int idx = tid; idx < T; idx += 1024) bkt[idx] = bin[idx];
  #pragma unroll
  for (int i = 0; i < 4; ++i) cnt[tid + i * 1024] = 0;
  __syncthreads();

  const int wave = tid >> 6, lane = tid & 63;
  const unsigned long long lt = (1ull << lane) - 1ull;
  #pragma unroll
  for (int cc = 0; cc < 4; ++cc) {
    int chunk = wave * 4 + cc;
    int e = bkt[chunk * 64 + lane];
    unsigned long long m = ~0ull;
    #pragma unroll
    for (int bb = 0; bb < 6; ++bb) {
      unsigned long long mb = __ballot(((e >> bb) & 1) != 0);
      m &= ((e >> bb) & 1) ? mb : ~mb;
    }
    unsigned long long below = m & lt;
    rnk[chunk * 64 + lane] = (unsigned short)__popcll(below);
    if (below == 0ull)
      cnt[e * 64 + chunk] = (unsigned int)__popcll(m);
  }
  __syncthreads();
  if (tid < 64) {
    unsigned int run = 0;
    for (int c = 0; c < 64; ++c) {
      unsigned int v = cnt[tid * 64 + c];
      cnt[tid * 64 + c] = run;
      run += v;
    }
    btot[tid] = run;
  }
  __syncthreads();
  if (tid == 0) {
    unsigned int run = 0;
    for (int bb = 0; bb < 64; ++bb) { bbase[bb] = run; run += btot[bb]; }
  }
  __syncthreads();
  for (int idx = tid; idx < T; idx += 1024) {
    int e = bkt[idx];
    int c = idx >> 6;
    int pos = (int)(bbase[e] + cnt[e * 64 + c] + rnk[idx]);
    perm[(size_t)seg * T + pos] = idx;
  }
}

// ---------------------------------------------------------------------------
// K3: per-bucket attention. TWO barriers: s2 (K staged) + sB (LK reads done +
// V^T visible). P write->read is same-wave (in-order DS), no barrier needed.
// V gather issued AFTER s2 so its latency hides under QK MFMAs.
// fp16, max-free softmax (raw v_exp), unnormalized o_u (exact combine).
// LDS 32KB -> 5 blocks/CU. grid 8192 (XCD-swizzled), block 256.
// ---------------------------------------------------------------------------
__global__ __launch_bounds__(256, 5) void k_attn18(
    const unsigned short* __restrict__ khf, const unsigned short* __restrict__ vhf,
    const int* __restrict__ perm, const float* __restrict__ norm025,
    __half* __restrict__ o_ws, float* __restrict__ lsum_ws) {
  __shared__ __align__(16) char smem[32768];
  constexpr int LK  = 0;       // ph1: Khat [128 kv][128B fp16] SWZ128
  constexpr int LP  = 0;       // ph2: P [64 q][256B fp16 = 128 kv] SWZ256
  constexpr int LVT = 16384;   // V^T [64 d][256B fp16 = 128 tokens] SWZ256

  const int tid = threadIdx.x;
  // XCD-aware bijective swizzle (8192 % 8 == 0): XCD x gets hash r = x.
  const int wg = ((int)blockIdx.x & 7) * 1024 + ((int)blockIdx.x >> 3);
  const int n = wg & 63, bh = (wg >> 6) & 15, r = wg >> 10;
  const size_t rowbase = (size_t)bh * T;
  const size_t ps = ((size_t)r * BHN + bh) * T;
  const int base_own = n * 64;
  const int base_prev = ((n + 63) & 63) * 64;

  const int wid = tid >> 6, lane = tid & 63;
  const int lr = lane & 15, lg = lane >> 4;

  const int qtok = perm[ps + base_own + 16 * wid + lr];
  const float scale = norm025[rowbase + qtok];

  // V-gather token indices (perm reads early; data loads deferred past s2)
  const int vj0 = (tid & 63) * 2;         // token pair (vj0, vj0+1)
  const int vd0 = (tid >> 6) * 16;        // d range [vd0, vd0+16)
  int vt[2];
  #pragma unroll
  for (int j = 0; j < 2; ++j) {
    int src = (vj0 + j < 64) ? (base_own + vj0 + j) : (base_prev + vj0 + j - 64);
    vt[j] = perm[ps + src];
  }

  // ---- K staging: global_load_lds, linear dest + inverse-swizzled source ----
  #pragma unroll
  for (int it = 0; it < 4; ++it) {
    int unit = it * 256 + tid;
    int row = unit >> 3, sl = unit & 7;
    int ssl = sl ^ (row & 7);
    int src = (row < 64) ? (base_own + row) : (base_prev + (row - 64));
    int tokr = perm[ps + src];
    async_load16(&khf[(rowbase + (size_t)tokr) * 64 + ssl * 8], smem + LK + unit * 16);
  }
  __syncthreads();  // s2: K staged (drains K loads only — V not yet issued)

  // ---- V gather issue (completes under QK MFMAs) ----
  uint4 VA0, VA1, VB0, VB1;
  {
    const uint4* pa_ = (const uint4*)&vhf[(rowbase + (size_t)vt[0]) * 64 + vd0];
    const uint4* pb_ = (const uint4*)&vhf[(rowbase + (size_t)vt[1]) * 64 + vd0];
    VA0 = pa_[0]; VA1 = pa_[1];
    VB0 = pb_[0]; VB1 = pb_[1];
  }

  // B frag = own q row, held in regs before P overlays LK
  f16x8 bq[2];
  #pragma unroll
  for (int ks = 0; ks < 2; ++ks)
    bq[ks] = *(const f16x8*)(smem + LK + SWZ128(16 * wid + lr, lg * 16 + ks * 64));

  // ---- QK: S^T[kv][q] = K . Q^T, 16 MFMA ----
  f32x4 c[8];
  #pragma unroll
  for (int t = 0; t < 8; ++t) c[t] = (f32x4){0.f, 0.f, 0.f, 0.f};
  #pragma unroll
  for (int t = 0; t < 8; ++t) {
    #pragma unroll
    for (int ks = 0; ks < 2; ++ks) {
      f16x8 ak = *(const f16x8*)(smem + LK + SWZ128(16 * t + lr, lg * 16 + ks * 64));
      c[t] = mfma16f(ak, bq[ks], c[t]);
    }
  }

  // ---- V^T -> LVT (own region; visible to all waves after sB) ----
  #pragma unroll
  for (int dd = 0; dd < 16; ++dd) {
    unsigned aw = (dd < 8) ? u4get(VA0, dd >> 1) : u4get(VA1, (dd - 8) >> 1);
    unsigned bw = (dd < 8) ? u4get(VB0, dd >> 1) : u4get(VB1, (dd - 8) >> 1);
    unsigned w = (dd & 1) ? __builtin_amdgcn_perm(bw, aw, 0x07060302u)
                          : __builtin_amdgcn_perm(bw, aw, 0x05040100u);
    *(unsigned*)(smem + LVT + SWZ256(vd0 + dd, vj0 * 2)) = w;
  }

  // ---- self-mask: position diagonal (q row == kv row in 0..63) ----
  #pragma unroll
  for (int t = 0; t < 4; ++t) {
    #pragma unroll
    for (int rr = 0; rr < 4; ++rr)
      if (16 * t + 4 * lg + rr == 16 * wid + lr) c[t][rr] = -1e30f;
  }

  // ---- MAX-FREE softmax: |score| <= scale (<= ~2.2), raw v_exp_f32 ----
  const float sl2e = scale * 1.4426950408889634f;
  float ll = 0.f;
  #pragma unroll
  for (int t = 0; t < 8; ++t) {
    #pragma unroll
    for (int rr = 0; rr < 4; ++rr) {
      float e = fast_exp2(c[t][rr] * sl2e);
      c[t][rr] = e;
      ll += e;
    }
  }
  ll += __shfl_xor(ll, 16);
  ll += __shfl_xor(ll, 32);
  if (lg == 0) lsum_ws[ps + qtok] = ll;   // raw sum (no log)

  __syncthreads();  // sB: all LK reads done + all V^T writes visible

  // ---- P (unnormalized fp16) over LK — same-wave write->read, no barrier ----
  {
    const int prow = 16 * wid + lr;
    #pragma unroll
    for (int t = 0; t < 8; ++t) {
      unsigned u01 = cvtpk_f16(c[t][0], c[t][1]);
      unsigned u23 = cvtpk_f16(c[t][2], c[t][3]);
      *(uint2*)(smem + LP + SWZ256(prow, 32 * t + 8 * lg)) = make_uint2(u01, u23);
    }
  }

  // ---- PV: A = P row (q = 16w+lr), B = V^T rows (d), 16 MFMA ----
  f16x8 pa[4];
  #pragma unroll
  for (int ks = 0; ks < 4; ++ks)
    pa[ks] = *(const f16x8*)(smem + LP + SWZ256(16 * wid + lr, ks * 64 + lg * 16));
  f32x4 o[4];
  #pragma unroll
  for (int td = 0; td < 4; ++td) o[td] = (f32x4){0.f, 0.f, 0.f, 0.f};
  #pragma unroll
  for (int td = 0; td < 4; ++td) {
    #pragma unroll
    for (int ks = 0; ks < 4; ++ks) {
      f16x8 bv = *(const f16x8*)(smem + LVT + SWZ256(16 * td + lr, lg * 16 + ks * 64));
      o[td] = mfma16f(pa[ks], bv, o[td]);
    }
  }

  // ---- UNNORMALIZED fp16 O stores (otok via shuffle from qtok) ----
  #pragma unroll
  for (int rr = 0; rr < 4; ++rr) {
    int otok = __shfl(qtok, 4 * lg + rr);
    size_t gb = (ps + (size_t)otok) * 64 + lr;
    #pragma unroll
    for (int td = 0; td < 4; ++td)
      o_ws[gb + 16 * td] = __float2half(o[td][rr]);
  }
}

// ---------------------------------------------------------------------------
// K4: exact combine: out = (sum_r o_u[r]) / (sum_r l[r]). uint4 (16B) o_ws
// loads, 8 d per thread. grid (BH*T*8/256), block 256.
// ---------------------------------------------------------------------------
__global__ __launch_bounds__(256) void k_combine(const __half* __restrict__ o_ws,
                                                 const float* __restrict__ lsum_ws,
                                                 float* __restrict__ out) {
  const int gid = blockIdx.x * 256 + threadIdx.x;
  const int d8 = (gid & 7) * 8;
  const int row = gid >> 3;   // bh*T + t
  const int bh = row >> 12;
  const int t = row & (T - 1);

  float lsum = 0.f;
  #pragma unroll
  for (int r = 0; r < 8; ++r)
    lsum += lsum_ws[((size_t)r * BHN + bh) * T + t];
  float rcp = 1.0f / lsum;

  float acc[8];
  #pragma unroll
  for (int k = 0; k < 8; ++k) acc[k] = 0.f;
  #pragma unroll
  for (int r = 0; r < 8; ++r) {
    uint4 u = *(const uint4*)&o_ws[(((size_t)r * BHN + bh) * T + t) * 64 + d8];
    #pragma unroll
    for (int k = 0; k < 4; ++k) {
      __half2 h; __builtin_memcpy(&h, k == 0 ? &u.x : k == 1 ? &u.y : k == 2 ? &u.z : &u.w, 4);
      float2 f = __half22float2(h);
      acc[2 * k] += f.x; acc[2 * k + 1] += f.y;
    }
  }
  const int b = bh >> 3, hh = bh & 7;
  float* op = &out[(((size_t)b * T + t) * 8 + hh) * 64 + d8];
  *(float4*)&op[0] = make_float4(acc[0] * rcp, acc[1] * rcp, acc[2] * rcp, acc[3] * rcp);
  *(float4*)&op[4] = make_float4(acc[4] * rcp, acc[5] * rcp, acc[6] * rcp, acc[7] * rcp);
}

// ---------------------------------------------------------------------------
extern "C" void kernel_launch(void* const* d_in, const int* in_sizes, int n_in,
                              void* d_out, int out_size, void* d_ws, size_t ws_size,
                              hipStream_t stream) {
  const float* qk  = (const float*)d_in[0];
  const float* v   = (const float*)d_in[1];
  const float* rot = (const float*)d_in[2];
  float* out = (float*)d_out;

  // workspace layout (bytes) — total 95,158,272 (within proven budget)
  char* ws = (char*)d_ws;
  __half* o_ws          = (__half*)(ws);                      // 67,108,864
  int* perm             = (int*)(ws + 67108864);              //  8,388,608
  unsigned char* bkts   = (unsigned char*)(ws + 75497472);    //    524,288
  float* lsum_ws        = (float*)(ws + 76021760);            //  2,097,152
  float* norm025        = (float*)(ws + 78118912);            //    262,144
  unsigned short* khf   = (unsigned short*)(ws + 78381056);   //  8,388,608
  unsigned short* vhf   = (unsigned short*)(ws + 86769664);   //  8,388,608

  k_prepbkt<<<dim3(T / 64, BHN), 256, 0, stream>>>(qk, v, rot, khf, vhf, norm025, bkts);
  k_sort<<<dim3(NH * BHN), 1024, 0, stream>>>(bkts, perm);
  k_attn18<<<dim3(NB * BHN * NH), 256, 0, stream>>>(khf, vhf, perm, norm025,
                                                    o_ws, lsum_ws);
  k_combine<<<dim3((BHN * T * 8) / 256), 256, 0, stream>>>(o_ws, lsum_ws, out);
}